// Round 5
// baseline (445.932 us; speedup 1.0000x reference)
//
#include <hip/hip_runtime.h>

#define N_NODES 8192
#define E_EDGES 262144
#define EMBDSZ  64
#define NIN     16
#define K_STEPS 4
#define ROWCAP  96    // Poisson(32) realized row max over 8192 rows ~56; huge margin
#define NBLK    512   // 2 blocks/CU used, 4/CU capacity under launch_bounds -> safe residency
#define NTHR    256

typedef unsigned long long u64;
typedef unsigned u32;

// Re-initialize per call: row cursors + barrier words (ws is NOT re-poisoned
// between replays, and the barrier phase counter must start at 0 every call).
__global__ void init_kernel(u32* __restrict__ cursor, u32* __restrict__ bar) {
    int t = threadIdx.x;
    uint4 z = make_uint4(0, 0, 0, 0);
    #pragma unroll
    for (int i = 0; i < 8; ++i) ((uint4*)cursor)[t + i * NTHR] = z;  // 2048 uint4 = 8192 u32
    if (t < 2) bar[t] = 0;   // bar[0]=arrival count, bar[1]=released phase
}

// Monotone-phase grid barrier. All NBLK blocks must be co-resident (they are:
// 512 blocks, capacity 4/CU * 256 CU = 1024).
__device__ __forceinline__ void grid_barrier(u32* bar, u32 phase) {
    __syncthreads();
    if (threadIdx.x == 0) {
        __threadfence();  // release: flush this block's writes to coherence point
        u32 arrived = __hip_atomic_fetch_add(&bar[0], 1u, __ATOMIC_ACQ_REL,
                                             __HIP_MEMORY_SCOPE_AGENT);
        if (arrived == NBLK - 1) {
            __hip_atomic_store(&bar[0], 0u, __ATOMIC_RELAXED, __HIP_MEMORY_SCOPE_AGENT);
            __hip_atomic_store(&bar[1], phase, __ATOMIC_RELEASE, __HIP_MEMORY_SCOPE_AGENT);
        } else {
            while (__hip_atomic_load(&bar[1], __ATOMIC_ACQUIRE,
                                     __HIP_MEMORY_SCOPE_AGENT) < phase) {
                __builtin_amdgcn_s_sleep(1);
            }
        }
        __threadfence();  // acquire: invalidate local caches before re-reading data
    }
    __syncthreads();
}

// One persistent kernel, phases separated by grid barriers:
// P0: x0 = nf @ Emb                     (131072 threads, 1 output each)
// P1: bucket edges by row: {w|c|eid}    (2 edges/thread)
// P2: per-row LDS dedup (last-write-wins) + spmm step 0; kills persisted
// P3-P5: spmm steps 1-3                 (4 rows/wave)
__global__ void __launch_bounds__(NTHR, 4) fused_kernel(
    const float* __restrict__ nf,
    const int*   __restrict__ ei,
    const float* __restrict__ ew,
    const float* __restrict__ emb,
    float* __restrict__ out,
    float* __restrict__ x0,
    u32*   __restrict__ cursor,
    u64*   __restrict__ rowdat,
    u32*   __restrict__ bar)
{
    __shared__ float semb[EMBDSZ * NIN];
    __shared__ u32   slo[4][ROWCAP];
    __shared__ float sw [4][ROWCAP];

    const int b = blockIdx.x, tid = threadIdx.x;
    const int wid = tid >> 6, lane = tid & 63;
    const int sub = lane >> 4, j = lane & 15;

    // ---- P0: embed ----
    for (int i = tid; i < EMBDSZ * NIN; i += NTHR) semb[i] = emb[i];
    __syncthreads();
    {
        int gid = b * NTHR + tid;             // [0, 131072) == N_NODES*NIN
        int n = gid >> 4, jj = gid & 15;
        float acc = 0.f;
        #pragma unroll
        for (int k = 0; k < EMBDSZ; ++k) acc += nf[n * EMBDSZ + k] * semb[k * NIN + jj];
        x0[n * NIN + jj] = acc;
    }
    grid_barrier(bar, 1);

    // ---- P1: scatter edges into row buckets ----
    #pragma unroll
    for (int e = b * NTHR + tid; e < E_EDGES; e += NBLK * NTHR) {
        u32 r  = (u32)ei[e];
        u32 c  = (u32)ei[E_EDGES + e];
        u32 wb = __float_as_uint(ew[e]);
        u32 slot = atomicAdd(&cursor[r], 1u);
        if (slot < ROWCAP)
            rowdat[(size_t)r * ROWCAP + slot] =
                ((u64)wb << 32) | ((u64)c << 18) | (u64)(u32)e;
    }
    grid_barrier(bar, 2);

    // ---- P2: dedup (LDS) + spmm step 0 ----
    #pragma unroll
    for (int rr = 0; rr < 4; ++rr) {
        int row = (b * 4 + wid) * 4 + rr;                 // waves*4 rows = 8192
        u32 len = min(cursor[row], (u32)ROWCAP);
        size_t base = (size_t)row * ROWCAP;
        for (u32 i = lane; i < len; i += 64) {
            u64 v = rowdat[base + i];
            slo[wid][i] = (u32)v;                          // (c<<18)|eid
            sw [wid][i] = __uint_as_float((u32)(v >> 32)); // weight
        }
        __syncthreads();
        for (u32 i = lane; i < len; i += 64) {
            u32 lo = slo[wid][i];
            bool dead = false;
            for (u32 q = 0; q < len; ++q) {
                u32 o = slo[wid][q];
                dead |= ((o >> 18) == (lo >> 18)) && (o > lo);
            }
            if (dead) {
                sw[wid][i] = 0.f;
                // persist kill for steps 1-3 (device-scope store: readers may be
                // on another XCD after the next barrier)
                __hip_atomic_store(&((u32*)&rowdat[base + i])[1], 0u,
                                   __ATOMIC_RELAXED, __HIP_MEMORY_SCOPE_AGENT);
            }
        }
        __syncthreads();
        float acc = 0.f;
        for (u32 i = sub; i < len; i += 4)
            acc += sw[wid][i] * x0[(slo[wid][i] >> 18) * NIN + j];
        acc += __shfl_xor(acc, 16);
        acc += __shfl_xor(acc, 32);
        if (sub == 0) out[row * NIN + j] = acc;
        __syncthreads();
    }

    // ---- P3..P5: spmm steps 1..3 ----
    for (int k = 1; k < K_STEPS; ++k) {
        grid_barrier(bar, 2 + k);
        const float* hin  = out + (size_t)(k - 1) * N_NODES * NIN;
        float*       hout = out + (size_t)k * N_NODES * NIN;
        #pragma unroll
        for (int rr = 0; rr < 4; ++rr) {
            int row = (b * 4 + wid) * 4 + rr;
            u32 len = min(cursor[row], (u32)ROWCAP);
            const u64* rp = rowdat + (size_t)row * ROWCAP;
            float acc = 0.f;
            for (u32 i = sub; i < len; i += 4) {
                u64 v = rp[i];
                acc += __uint_as_float((u32)(v >> 32)) *
                       hin[(((u32)(v >> 18)) & 0x1FFFu) * NIN + j];
            }
            acc += __shfl_xor(acc, 16);
            acc += __shfl_xor(acc, 32);
            if (sub == 0) hout[row * NIN + j] = acc;
        }
    }
}

extern "C" void kernel_launch(void* const* d_in, const int* in_sizes, int n_in,
                              void* d_out, int out_size, void* d_ws, size_t ws_size,
                              hipStream_t stream) {
    (void)in_sizes; (void)n_in; (void)out_size; (void)ws_size;
    const float* nf  = (const float*)d_in[0];
    const int*   ei  = (const int*)d_in[1];
    const float* ew  = (const float*)d_in[2];
    const float* emb = (const float*)d_in[3];
    float* out = (float*)d_out;

    char* ws = (char*)d_ws;
    size_t off = 0;
    auto alloc = [&](size_t bytes) {
        void* p = ws + off;
        off += (bytes + 255) & ~(size_t)255;
        return p;
    };
    u64*   rowdat = (u64*)  alloc((size_t)N_NODES * ROWCAP * 8);   // 6 MB
    float* x0     = (float*)alloc((size_t)N_NODES * NIN * 4);      // 512 KB
    u32*   cursor = (u32*)  alloc((size_t)N_NODES * 4);            // 32 KB
    u32*   bar    = (u32*)  alloc(256);

    init_kernel<<<1, NTHR, 0, stream>>>(cursor, bar);
    fused_kernel<<<NBLK, NTHR, 0, stream>>>(nf, ei, ew, emb, out, x0,
                                            cursor, rowdat, bar);
}

// Round 6
// 148.565 us; speedup vs baseline: 3.0016x; 3.0016x over previous
//
#include <hip/hip_runtime.h>

#define N_NODES 8192
#define E_EDGES 262144
#define EMBDSZ  64
#define NIN     16
#define K_STEPS 4
#define ROWCAP  96    // Poisson(32) realized row max over 8192 rows ~56; huge margin
#define NBLK    512   // 2 blocks/CU used, 4/CU capacity under launch_bounds -> co-resident
#define NTHR    256
#define NGRP    16
#define GRPSZ   32    // NBLK / NGRP

typedef unsigned long long u64;
typedef unsigned u32;

// Relaxed agent-scope ops compile to sc1 (device-coherent, IF-homed) accesses
// WITHOUT the buffer_inv/buffer_wbl2 cache maintenance that acquire/release emit.
#define AT_LOAD(p)     __hip_atomic_load((p), __ATOMIC_RELAXED, __HIP_MEMORY_SCOPE_AGENT)
#define AT_STORE(p, v) __hip_atomic_store((p), (v), __ATOMIC_RELAXED, __HIP_MEMORY_SCOPE_AGENT)
#define AT_ADD(p, v)   __hip_atomic_fetch_add((p), (v), __ATOMIC_RELAXED, __HIP_MEMORY_SCOPE_AGENT)

// Per-call re-init: row cursors + barrier words (monotone counters start at 0).
__global__ void init_kernel(u32* __restrict__ cursor, u32* __restrict__ bar) {
    int t = threadIdx.x;
    uint4 z = make_uint4(0, 0, 0, 0);
    #pragma unroll
    for (int i = 0; i < 8; ++i) ((uint4*)cursor)[t + i * NTHR] = z;  // 8192 u32
    ((uint4*)bar)[t] = z;                                            // 1024 u32
}

// Tree grid barrier, monotone phases (1,2,3,...), no counter resets.
// bar layout (u32 idx): grp g: cnt @ g*32, rel @ g*32+16; top: cnt @ 512, rel @ 544.
// Protocol: data stores are sc1 write-through; each wave drains vmcnt before
// s_barrier, so arrival implies this block's data is at the coherence point.
// Spin: RELAXED sc1 loads (no inv per iteration). After release observed: ONE
// acquire-agent fence (single buffer_inv) dumps stale-clean L1/L2 lines.
__device__ __forceinline__ void grid_barrier(u32* bar, u32 phase) {
    asm volatile("s_waitcnt vmcnt(0)" ::: "memory");
    __syncthreads();
    if (threadIdx.x == 0) {
        u32 g = blockIdx.x >> 5;
        u32* gcnt = bar + g * 32;
        u32* grel = bar + g * 32 + 16;
        u32* tcnt = bar + 512;
        u32* trel = bar + 544;
        if (AT_ADD(gcnt, 1u) == phase * GRPSZ - 1u) {      // last of group
            if (AT_ADD(tcnt, 1u) == phase * NGRP - 1u) {   // last of grid
                AT_STORE(trel, phase);
            } else {
                while (AT_LOAD(trel) < phase) __builtin_amdgcn_s_sleep(2);
            }
            AT_STORE(grel, phase);
        } else {
            while (AT_LOAD(grel) < phase) __builtin_amdgcn_s_sleep(2);
        }
    }
    __builtin_amdgcn_fence(__ATOMIC_ACQUIRE, "agent");     // one buffer_inv
    __syncthreads();
}

// One persistent kernel:
// P0: embed (x0 = nf @ Emb) AND scatter edges by row (independent) | barrier
// P1: per-row LDS dedup (last-write-wins) + spmm step 0            | barrier
// P2..P4: spmm steps 1..3                                          | barriers between
__global__ void __launch_bounds__(NTHR, 4) fused_kernel(
    const float* __restrict__ nf,
    const int*   __restrict__ ei,
    const float* __restrict__ ew,
    const float* __restrict__ emb,
    float* __restrict__ out,
    float* __restrict__ x0,
    u32*   __restrict__ cursor,
    u64*   __restrict__ rowdat,
    u32*   __restrict__ bar)
{
    __shared__ float semb[EMBDSZ * NIN];
    __shared__ u32   slo[4][ROWCAP];
    __shared__ float sw [4][ROWCAP];

    const int b = blockIdx.x, tid = threadIdx.x;
    const int wid = tid >> 6, lane = tid & 63;
    const int sub = lane >> 4, j = lane & 15;

    // ---- P0a: embed (512*256 threads == N_NODES*NIN outputs) ----
    for (int i = tid; i < EMBDSZ * NIN; i += NTHR) semb[i] = emb[i];
    __syncthreads();
    {
        int gid = b * NTHR + tid;
        int n = gid >> 4, jj = gid & 15;
        float acc = 0.f;
        #pragma unroll
        for (int k = 0; k < EMBDSZ; ++k) acc += nf[n * EMBDSZ + k] * semb[k * NIN + jj];
        AT_STORE(&x0[n * NIN + jj], acc);
    }
    // ---- P0b: scatter edges into row buckets (2 edges/thread) ----
    for (int e = b * NTHR + tid; e < E_EDGES; e += NBLK * NTHR) {
        u32 r  = (u32)ei[e];
        u32 c  = (u32)ei[E_EDGES + e];
        u32 wb = __float_as_uint(ew[e]);
        u32 slot = atomicAdd(&cursor[r], 1u);              // device-scope by default
        if (slot < ROWCAP)
            AT_STORE(&rowdat[(size_t)r * ROWCAP + slot],
                     ((u64)wb << 32) | ((u64)c << 18) | (u64)(u32)e);
    }
    grid_barrier(bar, 1);

    // ---- P1: dedup (LDS) + spmm step 0 (4 rows per wave) ----
    #pragma unroll
    for (int rr = 0; rr < 4; ++rr) {
        int row = (b * 4 + wid) * 4 + rr;                  // 2048 waves * 4 = 8192
        u32 len = min(cursor[row], (u32)ROWCAP);
        size_t base = (size_t)row * ROWCAP;
        for (u32 i = lane; i < len; i += 64) {
            u64 v = rowdat[base + i];
            slo[wid][i] = (u32)v;                          // (c<<18)|eid
            sw [wid][i] = __uint_as_float((u32)(v >> 32)); // weight
        }
        __syncthreads();
        for (u32 i = lane; i < len; i += 64) {
            u32 lo = slo[wid][i];
            bool dead = false;
            for (u32 q = 0; q < len; ++q) {
                u32 o = slo[wid][q];
                dead |= ((o >> 18) == (lo >> 18)) && (o > lo);
            }
            if (dead) {
                sw[wid][i] = 0.f;
                AT_STORE(((u32*)&rowdat[base + i]) + 1, 0u);   // persist kill
            }
        }
        __syncthreads();
        float acc = 0.f;
        for (u32 i = sub; i < len; i += 4)
            acc += sw[wid][i] * x0[(slo[wid][i] >> 18) * NIN + j];
        acc += __shfl_xor(acc, 16);
        acc += __shfl_xor(acc, 32);
        if (sub == 0) AT_STORE(&out[row * NIN + j], acc);
        __syncthreads();
    }

    // ---- P2..P4: spmm steps 1..3 ----
    for (int k = 1; k < K_STEPS; ++k) {
        grid_barrier(bar, 1 + k);
        const float* hin  = out + (size_t)(k - 1) * N_NODES * NIN;
        float*       hout = out + (size_t)k * N_NODES * NIN;
        #pragma unroll
        for (int rr = 0; rr < 4; ++rr) {
            int row = (b * 4 + wid) * 4 + rr;
            u32 len = min(cursor[row], (u32)ROWCAP);
            const u64* rp = rowdat + (size_t)row * ROWCAP;
            float acc = 0.f;
            for (u32 i = sub; i < len; i += 4) {
                u64 v = rp[i];
                acc += __uint_as_float((u32)(v >> 32)) *
                       hin[(((u32)(v >> 18)) & 0x1FFFu) * NIN + j];
            }
            acc += __shfl_xor(acc, 16);
            acc += __shfl_xor(acc, 32);
            if (sub == 0) AT_STORE(&hout[row * NIN + j], acc);
        }
    }
}

extern "C" void kernel_launch(void* const* d_in, const int* in_sizes, int n_in,
                              void* d_out, int out_size, void* d_ws, size_t ws_size,
                              hipStream_t stream) {
    (void)in_sizes; (void)n_in; (void)out_size; (void)ws_size;
    const float* nf  = (const float*)d_in[0];
    const int*   ei  = (const int*)d_in[1];
    const float* ew  = (const float*)d_in[2];
    const float* emb = (const float*)d_in[3];
    float* out = (float*)d_out;

    char* ws = (char*)d_ws;
    size_t off = 0;
    auto alloc = [&](size_t bytes) {
        void* p = ws + off;
        off += (bytes + 255) & ~(size_t)255;
        return p;
    };
    u64*   rowdat = (u64*)  alloc((size_t)N_NODES * ROWCAP * 8);   // 6 MB
    float* x0     = (float*)alloc((size_t)N_NODES * NIN * 4);      // 512 KB
    u32*   cursor = (u32*)  alloc((size_t)N_NODES * 4);            // 32 KB
    u32*   bar    = (u32*)  alloc(4096);                           // barrier words

    init_kernel<<<1, NTHR, 0, stream>>>(cursor, bar);
    fused_kernel<<<NBLK, NTHR, 0, stream>>>(nf, ei, ew, emb, out, x0,
                                            cursor, rowdat, bar);
}

// Round 7
// 73.445 us; speedup vs baseline: 6.0716x; 2.0228x over previous
//
#include <hip/hip_runtime.h>

#define N_NODES 8192
#define E_EDGES 262144
#define EMBDSZ  64
#define NIN     16
#define K_STEPS 4
#define ROWCAP  96    // Poisson(32) realized row max ~56-60 over 8192 rows
#define NBLK    1024  // 4 blocks/CU -> all co-resident, 4 waves/SIMD
#define NTHR    256
#define NGRP    32
#define GRPSZ   32    // NBLK / NGRP

typedef unsigned long long u64;
typedef unsigned u32;

// Relaxed agent-scope ops: sc1 accesses served at the device coherence point,
// with NO buffer_inv / buffer_wbl2 cache maintenance (acquire/release emit those).
#define AT_LOAD(p)     __hip_atomic_load((p), __ATOMIC_RELAXED, __HIP_MEMORY_SCOPE_AGENT)
#define AT_STORE(p, v) __hip_atomic_store((p), (v), __ATOMIC_RELAXED, __HIP_MEMORY_SCOPE_AGENT)
#define AT_ADD(p, v)   __hip_atomic_fetch_add((p), (v), __ATOMIC_RELAXED, __HIP_MEMORY_SCOPE_AGENT)

// Per-call re-init: row cursors + barrier words (monotone counters start at 0).
__global__ void init_kernel(u32* __restrict__ cursor, u32* __restrict__ bar) {
    int t = threadIdx.x;
    uint4 z = make_uint4(0, 0, 0, 0);
    #pragma unroll
    for (int i = 0; i < 8; ++i) ((uint4*)cursor)[t + i * NTHR] = z;  // 8192 u32
    ((uint4*)bar)[t] = z;                     // 1024 u32
    if (t < 16) ((uint4*)bar)[256 + t] = z;   // + top-level words
}

// 2-level tree barrier, monotone phases, relaxed polling, NO cache maintenance.
// Correctness contract: all cross-phase data is written with sc1 (AT_STORE) and
// every consumer's first read of a line happens AFTER the producing phase
// (first-touch) -> normal cached loads fetch the coherent copy from IF; no line
// is ever re-read after being remotely modified (dedup writes to a FRESH buffer).
// bar layout (u32): grp g: cnt @ g*32, rel @ g*32+16; top: cnt @ 1024, rel @ 1040.
__device__ __forceinline__ void grid_barrier(u32* bar, u32 phase) {
    asm volatile("s_waitcnt vmcnt(0)" ::: "memory");  // drain this wave's sc1 stores
    __syncthreads();                                   // => whole block's data is at IF
    if (threadIdx.x == 0) {
        u32 g = (u32)blockIdx.x >> 5;
        u32* gcnt = bar + g * 32;
        u32* grel = bar + g * 32 + 16;
        u32* tcnt = bar + 1024;
        u32* trel = bar + 1040;
        if (AT_ADD(gcnt, 1u) == phase * GRPSZ - 1u) {      // last of group
            if (AT_ADD(tcnt, 1u) == phase * NGRP - 1u) {   // last of grid
                AT_STORE(trel, phase);
            } else {
                while (AT_LOAD(trel) < phase) __builtin_amdgcn_s_sleep(4);
            }
            AT_STORE(grel, phase);
        } else {
            while (AT_LOAD(grel) < phase) __builtin_amdgcn_s_sleep(4);
        }
    }
    __syncthreads();
}

// Phases:
// P0: embed x0 (blocks<512) + scatter edges->rowdat {w|c|eid} (all)   | barrier
// P1: per-row LDS dedup -> compacted clean row to rowdat2/cursor2,
//     + spmm step 0 from LDS (x0 gather)                              | barrier
// P2..P4: spmm steps 1..3 from rowdat2 (16 slots x 4 feature-groups)  | barriers
__global__ void __launch_bounds__(NTHR, 4) fused_kernel(
    const float* __restrict__ nf,
    const int*   __restrict__ ei,
    const float* __restrict__ ew,
    const float* __restrict__ emb,
    float* __restrict__ out,
    float* __restrict__ x0,
    u32*   __restrict__ cursor,
    u64*   __restrict__ rowdat,
    u64*   __restrict__ rowdat2,
    u32*   __restrict__ cursor2,
    u32*   __restrict__ bar)
{
    __shared__ float semb[EMBDSZ * NIN];
    __shared__ u32   slo[4][ROWCAP];
    __shared__ float swt[4][ROWCAP];
    __shared__ u32   scnt[4];

    const int b = blockIdx.x, tid = threadIdx.x;
    const int wid = tid >> 6, lane = tid & 63;
    const int slane = lane & 15, f4 = lane >> 4;   // 16 edge-slots x 4 feature-groups

    // ---- P0a: embed (blocks 0-511, one output each) ----
    if (b < 512) {
        for (int i = tid; i < EMBDSZ * NIN; i += NTHR) semb[i] = emb[i];
        __syncthreads();
        int gid = b * NTHR + tid;
        int n = gid >> 4, jj = gid & 15;
        float acc = 0.f;
        #pragma unroll
        for (int k = 0; k < EMBDSZ; ++k) acc += nf[n * EMBDSZ + k] * semb[k * NIN + jj];
        AT_STORE(&x0[n * NIN + jj], acc);
    }
    // ---- P0b: scatter (exactly 1 edge per thread) ----
    {
        int e = b * NTHR + tid;
        u32 r  = (u32)ei[e];
        u32 c  = (u32)ei[E_EDGES + e];
        u32 wb = __float_as_uint(ew[e]);
        u32 slot = atomicAdd(&cursor[r], 1u);   // far atomic, no cache allocate
        if (slot < ROWCAP)
            AT_STORE(&rowdat[(size_t)r * ROWCAP + slot],
                     ((u64)wb << 32) | (u64)(c << 18) | (u64)(u32)e);
    }
    grid_barrier(bar, 1);

    // ---- P1: dedup + compact + spmm step 0 (2 rows per wave) ----
    const int wave = b * 4 + wid;   // 4096 waves, 8192 rows
    #pragma unroll
    for (int rr = 0; rr < 2; ++rr) {
        int row = wave * 2 + rr;
        u32 len = min(cursor[row], (u32)ROWCAP);
        size_t base = (size_t)row * ROWCAP;
        if (lane == 0) scnt[wid] = 0;
        for (u32 i = lane; i < len; i += 64) {
            u64 v = rowdat[base + i];
            slo[wid][i] = (u32)v;                          // (c<<18)|eid
            swt[wid][i] = __uint_as_float((u32)(v >> 32));
        }
        // wave-private LDS slice; same-wave LDS ops are ordered -> no __syncthreads
        for (u32 i = lane; i < len; i += 64) {
            u32 lo = slo[wid][i];
            bool dead = false;
            for (u32 q = 0; q < len; ++q) {
                u32 o = slo[wid][q];
                dead |= ((o >> 18) == (lo >> 18)) && (o > lo);
            }
            if (dead) {
                swt[wid][i] = 0.f;
            } else {
                u32 pos = atomicAdd(&scnt[wid], 1u);       // LDS atomic
                AT_STORE(&rowdat2[(size_t)row * ROWCAP + pos],
                         ((u64)(u32)__float_as_uint(swt[wid][i]) << 32) |
                         (u64)(lo >> 18));                  // {w:32 | c:13}
            }
        }
        if (lane == 0) AT_STORE(&cursor2[row], scnt[wid]);
        // spmm0: LDS weights (dups zeroed) x x0 gather
        float4 acc = make_float4(0.f, 0.f, 0.f, 0.f);
        for (u32 i = slane; i < len; i += 16) {
            float w = swt[wid][i];
            u32 c = slo[wid][i] >> 18;
            const float4 h = *(const float4*)&x0[c * NIN + f4 * 4];
            acc.x += w * h.x; acc.y += w * h.y; acc.z += w * h.z; acc.w += w * h.w;
        }
        #pragma unroll
        for (int d = 1; d < 16; d <<= 1) {
            acc.x += __shfl_xor(acc.x, d);
            acc.y += __shfl_xor(acc.y, d);
            acc.z += __shfl_xor(acc.z, d);
            acc.w += __shfl_xor(acc.w, d);
        }
        if (slane == 0) {
            float* o = &out[row * NIN + f4 * 4];
            AT_STORE(o + 0, acc.x); AT_STORE(o + 1, acc.y);
            AT_STORE(o + 2, acc.z); AT_STORE(o + 3, acc.w);
        }
        __syncthreads();   // LDS slice reuse between rr iterations
    }

    // ---- P2..P4: spmm steps 1..3 from compacted rows ----
    for (int k = 1; k < K_STEPS; ++k) {
        grid_barrier(bar, 1 + k);
        const float* hin  = out + (size_t)(k - 1) * N_NODES * NIN;
        float*       hout = out + (size_t)k * N_NODES * NIN;
        #pragma unroll
        for (int rr = 0; rr < 2; ++rr) {
            int row = wave * 2 + rr;
            u32 len2 = cursor2[row];
            const u64* rp = rowdat2 + (size_t)row * ROWCAP;
            float4 acc = make_float4(0.f, 0.f, 0.f, 0.f);
            for (u32 i = slane; i < len2; i += 16) {
                u64 v = rp[i];
                float w = __uint_as_float((u32)(v >> 32));
                u32 c = (u32)v & 0x1FFFu;
                const float4 h = *(const float4*)&hin[c * NIN + f4 * 4];
                acc.x += w * h.x; acc.y += w * h.y; acc.z += w * h.z; acc.w += w * h.w;
            }
            #pragma unroll
            for (int d = 1; d < 16; d <<= 1) {
                acc.x += __shfl_xor(acc.x, d);
                acc.y += __shfl_xor(acc.y, d);
                acc.z += __shfl_xor(acc.z, d);
                acc.w += __shfl_xor(acc.w, d);
            }
            if (slane == 0) {
                float* o = &hout[row * NIN + f4 * 4];
                AT_STORE(o + 0, acc.x); AT_STORE(o + 1, acc.y);
                AT_STORE(o + 2, acc.z); AT_STORE(o + 3, acc.w);
            }
        }
    }
}

extern "C" void kernel_launch(void* const* d_in, const int* in_sizes, int n_in,
                              void* d_out, int out_size, void* d_ws, size_t ws_size,
                              hipStream_t stream) {
    (void)in_sizes; (void)n_in; (void)out_size; (void)ws_size;
    const float* nf  = (const float*)d_in[0];
    const int*   ei  = (const int*)d_in[1];
    const float* ew  = (const float*)d_in[2];
    const float* emb = (const float*)d_in[3];
    float* out = (float*)d_out;

    char* ws = (char*)d_ws;
    size_t off = 0;
    auto alloc = [&](size_t bytes) {
        void* p = ws + off;
        off += (bytes + 255) & ~(size_t)255;
        return p;
    };
    u64*   rowdat  = (u64*)alloc((size_t)N_NODES * ROWCAP * 8);   // 6.3 MB
    u64*   rowdat2 = (u64*)alloc((size_t)N_NODES * ROWCAP * 8);   // 6.3 MB
    float* x0      = (float*)alloc((size_t)N_NODES * NIN * 4);    // 512 KB
    u32*   cursor  = (u32*)alloc((size_t)N_NODES * 4);            // 32 KB
    u32*   cursor2 = (u32*)alloc((size_t)N_NODES * 4);            // 32 KB
    u32*   bar     = (u32*)alloc(8192);                           // barrier words

    init_kernel<<<1, NTHR, 0, stream>>>(cursor, bar);
    fused_kernel<<<NBLK, NTHR, 0, stream>>>(nf, ei, ew, emb, out, x0,
                                            cursor, rowdat, rowdat2, cursor2, bar);
}

// Round 8
// 69.369 us; speedup vs baseline: 6.4284x; 1.0588x over previous
//
#include <hip/hip_runtime.h>

#define N_NODES 8192
#define E_EDGES 262144
#define EMBDSZ  64
#define NIN     16
#define K_STEPS 4
#define ROWCAP  96    // Poisson(32) realized row max ~56-60 over 8192 rows
#define NBLK    1024  // 4 blocks/CU -> co-resident under __launch_bounds__(256,4)
#define NTHR    256
#define NGRP    32
#define GRPSZ   32    // NBLK / NGRP

typedef unsigned long long u64;
typedef unsigned u32;
typedef float f32x4 __attribute__((ext_vector_type(4)));

// Relaxed agent-scope ops: sc1 accesses served at the device coherence point,
// no buffer_inv / buffer_wbl2 cache maintenance.
#define AT_LOAD(p)     __hip_atomic_load((p), __ATOMIC_RELAXED, __HIP_MEMORY_SCOPE_AGENT)
#define AT_STORE(p, v) __hip_atomic_store((p), (v), __ATOMIC_RELAXED, __HIP_MEMORY_SCOPE_AGENT)
#define AT_ADD(p, v)   __hip_atomic_fetch_add((p), (v), __ATOMIC_RELAXED, __HIP_MEMORY_SCOPE_AGENT)

// Vector device-coherent (sc1) stores. NOT vmcnt-tracked by the compiler ->
// the grid barrier drains vmcnt(0) in every wave before arrival.
__device__ __forceinline__ void store_f4_sc1(float* p, f32x4 v) {
    asm volatile("global_store_dwordx4 %0, %1, off sc1" :: "v"(p), "v"(v) : "memory");
}
__device__ __forceinline__ void store_u64_sc1(u64* p, u64 v) {
    asm volatile("global_store_dwordx2 %0, %1, off sc1" :: "v"(p), "v"(v) : "memory");
}

// Per-call re-init: row cursors (8192 u32) + barrier words (2048 u32).
__global__ void init_kernel(u32* __restrict__ cursor, u32* __restrict__ bar) {
    int t = threadIdx.x;
    uint4 z = make_uint4(0, 0, 0, 0);
    #pragma unroll
    for (int i = 0; i < 8; ++i) ((uint4*)cursor)[t + i * NTHR] = z;
    #pragma unroll
    for (int i = 0; i < 2; ++i) ((uint4*)bar)[t + i * NTHR] = z;
}

// Tree arrival + broadcast release, monotone phases, relaxed sc1 polling.
// Layout (u32 idx, 64B stride/line): gcnt[g]=bar[g*16] (g<32), tcnt=bar[512],
// grel[g]=bar[528+g*16]. Last-of-grid writes ALL grel words (single poll level).
__device__ __forceinline__ void grid_barrier(u32* bar, u32 phase) {
    asm volatile("s_waitcnt vmcnt(0)" ::: "memory");  // every wave drains far stores
    __syncthreads();                                   // block's data is at IF
    if (threadIdx.x == 0) {
        u32 g = (u32)blockIdx.x >> 5;
        if (AT_ADD(&bar[g * 16], 1u) == phase * GRPSZ - 1u) {       // last of group
            if (AT_ADD(&bar[512], 1u) == phase * NGRP - 1u) {       // last of grid
                #pragma unroll
                for (u32 gg = 0; gg < NGRP; ++gg)
                    AT_STORE(&bar[528 + gg * 16], phase);           // broadcast release
            }
        }
        while (AT_LOAD(&bar[528 + g * 16]) < phase) __builtin_amdgcn_s_sleep(1);
    }
    __syncthreads();
}

// Phases:
// P0: embed x0 (ALL blocks, 2 threads/output, split-K + shfl merge)
//     + scatter edges->rowdat {w:32|c:13|eid:18} (1 edge/thread)      | barrier
// P1: per-row LDS dedup -> compacted {w:32|c:13} rows to rowdat2/cursor2,
//     + spmm step 0 from LDS (x0 gather)                              | barrier
// P2..P4: spmm steps 1..3 (16 edge-slots x 4 feature-groups, f32x4)   | barriers
__global__ void __launch_bounds__(NTHR, 4) fused_kernel(
    const float* __restrict__ nf,
    const int*   __restrict__ ei,
    const float* __restrict__ ew,
    const float* __restrict__ emb,
    float* __restrict__ out,
    float* __restrict__ x0,
    u32*   __restrict__ cursor,
    u64*   __restrict__ rowdat,
    u64*   __restrict__ rowdat2,
    u32*   __restrict__ cursor2,
    u32*   __restrict__ bar)
{
    __shared__ float semb[EMBDSZ * NIN];
    __shared__ u32   slo[4][ROWCAP];
    __shared__ float swt[4][ROWCAP];
    __shared__ u32   scnt[4];

    const int b = blockIdx.x, tid = threadIdx.x;
    const int wid = tid >> 6, lane = tid & 63;
    const int slane = lane & 15, f4 = lane >> 4;   // 16 edge-slots x 4 feature-groups

    // ---- P0a: embed, all blocks. gt = 2 threads per output, K split 32+32 ----
    for (int i = tid; i < EMBDSZ * NIN; i += NTHR) semb[i] = emb[i];
    __syncthreads();
    {
        int gt = b * NTHR + tid;            // 0..262143
        int o = gt >> 1, half = gt & 1;     // output 0..131071
        int n = o >> 4, jj = o & 15;
        const float* nfp = nf + n * EMBDSZ + half * 32;
        const float* ep  = semb + half * 32 * NIN + jj;
        float acc = 0.f;
        #pragma unroll
        for (int k = 0; k < 32; ++k) acc += nfp[k] * ep[k * NIN];
        acc += __shfl_xor(acc, 1);
        if (half == 0) AT_STORE(&x0[o], acc);
    }
    // ---- P0b: scatter (exactly 1 edge per thread) ----
    {
        int e = b * NTHR + tid;
        u32 r  = (u32)ei[e];
        u32 c  = (u32)ei[E_EDGES + e];
        u32 wb = __float_as_uint(ew[e]);
        u32 slot = atomicAdd(&cursor[r], 1u);
        if (slot < ROWCAP)
            store_u64_sc1(&rowdat[(size_t)r * ROWCAP + slot],
                          ((u64)wb << 32) | (u64)(c << 18) | (u64)(u32)e);
    }
    grid_barrier(bar, 1);

    // ---- P1: dedup + compact + spmm step 0 (2 rows per wave, wave-private LDS) ----
    const int wave = b * 4 + wid;   // 4096 waves, 8192 rows
    #pragma unroll
    for (int rr = 0; rr < 2; ++rr) {
        int row = wave * 2 + rr;
        u32 len = min(cursor[row], (u32)ROWCAP);
        size_t base = (size_t)row * ROWCAP;
        if (lane == 0) scnt[wid] = 0;
        for (u32 i = lane; i < len; i += 64) {
            u64 v = rowdat[base + i];
            slo[wid][i] = (u32)v;                          // (c<<18)|eid
            swt[wid][i] = __uint_as_float((u32)(v >> 32));
        }
        for (u32 i = lane; i < len; i += 64) {
            u32 lo = slo[wid][i];
            bool dead = false;
            for (u32 q = 0; q < len; ++q) {
                u32 o = slo[wid][q];
                dead |= ((o >> 18) == (lo >> 18)) && (o > lo);
            }
            if (dead) {
                swt[wid][i] = 0.f;
            } else {
                u32 pos = atomicAdd(&scnt[wid], 1u);       // LDS atomic
                store_u64_sc1(&rowdat2[(size_t)row * ROWCAP + pos],
                              ((u64)(u32)__float_as_uint(swt[wid][i]) << 32) |
                              (u64)(lo >> 18));            // {w:32 | c:13}
            }
        }
        if (lane == 0) AT_STORE(&cursor2[row], scnt[wid]);
        // spmm0 from LDS (dups zeroed) x x0 gather
        f32x4 acc = {0.f, 0.f, 0.f, 0.f};
        for (u32 i = slane; i < len; i += 16) {
            float w = swt[wid][i];
            u32 c = slo[wid][i] >> 18;
            f32x4 h = *(const f32x4*)&x0[c * NIN + f4 * 4];
            acc += w * h;
        }
        #pragma unroll
        for (int d = 1; d < 16; d <<= 1) {
            acc.x += __shfl_xor(acc.x, d);
            acc.y += __shfl_xor(acc.y, d);
            acc.z += __shfl_xor(acc.z, d);
            acc.w += __shfl_xor(acc.w, d);
        }
        if (slane == 0) store_f4_sc1(&out[row * NIN + f4 * 4], acc);
    }

    // ---- P2..P4: spmm steps 1..3 from compacted rows ----
    for (int k = 1; k < K_STEPS; ++k) {
        grid_barrier(bar, 1 + k);
        const float* hin  = out + (size_t)(k - 1) * N_NODES * NIN;
        float*       hout = out + (size_t)k * N_NODES * NIN;
        #pragma unroll
        for (int rr = 0; rr < 2; ++rr) {
            int row = wave * 2 + rr;
            u32 len2 = cursor2[row];
            const u64* rp = rowdat2 + (size_t)row * ROWCAP;
            f32x4 acc = {0.f, 0.f, 0.f, 0.f};
            for (u32 i = slane; i < len2; i += 16) {
                u64 v = rp[i];
                float w = __uint_as_float((u32)(v >> 32));
                u32 c = (u32)v & 0x1FFFu;
                f32x4 h = *(const f32x4*)&hin[c * NIN + f4 * 4];
                acc += w * h;
            }
            #pragma unroll
            for (int d = 1; d < 16; d <<= 1) {
                acc.x += __shfl_xor(acc.x, d);
                acc.y += __shfl_xor(acc.y, d);
                acc.z += __shfl_xor(acc.z, d);
                acc.w += __shfl_xor(acc.w, d);
            }
            if (slane == 0) store_f4_sc1(&hout[row * NIN + f4 * 4], acc);
        }
    }
}

extern "C" void kernel_launch(void* const* d_in, const int* in_sizes, int n_in,
                              void* d_out, int out_size, void* d_ws, size_t ws_size,
                              hipStream_t stream) {
    (void)in_sizes; (void)n_in; (void)out_size; (void)ws_size;
    const float* nf  = (const float*)d_in[0];
    const int*   ei  = (const int*)d_in[1];
    const float* ew  = (const float*)d_in[2];
    const float* emb = (const float*)d_in[3];
    float* out = (float*)d_out;

    char* ws = (char*)d_ws;
    size_t off = 0;
    auto alloc = [&](size_t bytes) {
        void* p = ws + off;
        off += (bytes + 255) & ~(size_t)255;
        return p;
    };
    u64*   rowdat  = (u64*)alloc((size_t)N_NODES * ROWCAP * 8);   // 6.3 MB
    u64*   rowdat2 = (u64*)alloc((size_t)N_NODES * ROWCAP * 8);   // 6.3 MB
    float* x0      = (float*)alloc((size_t)N_NODES * NIN * 4);    // 512 KB
    u32*   cursor  = (u32*)alloc((size_t)N_NODES * 4);            // 32 KB
    u32*   cursor2 = (u32*)alloc((size_t)N_NODES * 4);            // 32 KB
    u32*   bar     = (u32*)alloc(8192);                           // barrier words

    init_kernel<<<1, NTHR, 0, stream>>>(cursor, bar);
    fused_kernel<<<NBLK, NTHR, 0, stream>>>(nf, ei, ew, emb, out, x0,
                                            cursor, rowdat, rowdat2, cursor2, bar);
}

// Round 9
// 50.828 us; speedup vs baseline: 8.7733x; 1.3648x over previous
//
#include <hip/hip_runtime.h>

#define N_NODES 8192
#define E_EDGES 262144
#define EMBDSZ  64
#define NIN     16
#define K_STEPS 4
#define ROWCAP  96    // Poisson(32) realized row max ~56-60 over 8192 rows
#define NTHR    256

typedef unsigned long long u64;
typedef unsigned u32;
typedef float f32x4 __attribute__((ext_vector_type(4)));

// D1: zero row cursors (dispatch ordering guarantees visibility to D2).
__global__ void init_kernel(u32* __restrict__ cursor) {
    int t = blockIdx.x * NTHR + threadIdx.x;      // 4 blocks * 256 = 1024
    uint4 z = make_uint4(0, 0, 0, 0);
    ((uint4*)cursor)[t * 2]     = z;              // 2048 uint4 = 8192 u32
    ((uint4*)cursor)[t * 2 + 1] = z;
}

// D2: embed (2 threads per output, K split 32+32, shfl merge) + scatter
// edges into row buckets {w:32 | c:13 | eid:18}. 1024 blocks x 256.
__global__ void embed_scatter_kernel(const float* __restrict__ nf,
                                     const float* __restrict__ emb,
                                     const int*   __restrict__ ei,
                                     const float* __restrict__ ew,
                                     float* __restrict__ x0,
                                     u32*   __restrict__ cursor,
                                     u64*   __restrict__ rowdat) {
    __shared__ float semb[EMBDSZ * NIN];
    const int b = blockIdx.x, tid = threadIdx.x;
    for (int i = tid; i < EMBDSZ * NIN; i += NTHR) semb[i] = emb[i];
    __syncthreads();
    {
        int gt = b * NTHR + tid;            // 0..262143
        int o = gt >> 1, half = gt & 1;     // output 0..131071
        int n = o >> 4, jj = o & 15;
        const float* nfp = nf + n * EMBDSZ + half * 32;
        const float* ep  = semb + half * 32 * NIN + jj;
        float acc = 0.f;
        #pragma unroll
        for (int k = 0; k < 32; ++k) acc += nfp[k] * ep[k * NIN];
        acc += __shfl_xor(acc, 1);
        if (half == 0) x0[o] = acc;
    }
    {
        int e = b * NTHR + tid;             // exactly 1 edge per thread
        u32 r  = (u32)ei[e];
        u32 c  = (u32)ei[E_EDGES + e];
        u32 wb = __float_as_uint(ew[e]);
        u32 slot = atomicAdd(&cursor[r], 1u);
        if (slot < ROWCAP)
            rowdat[(size_t)r * ROWCAP + slot] =
                ((u64)wb << 32) | (u64)(c << 18) | (u64)(u32)e;
    }
}

// D3: per-row LDS dedup (last-write-wins by max eid) -> compacted {w:32|c:13}
// rows in rowdat2/cursor2, + spmm step 0 from LDS. 2 rows/wave, 8 rows/block.
__global__ void dedup_spmm0_kernel(const u32* __restrict__ cursor,
                                   const u64* __restrict__ rowdat,
                                   const float* __restrict__ x0,
                                   u64* __restrict__ rowdat2,
                                   u32* __restrict__ cursor2,
                                   float* __restrict__ out) {
    __shared__ u32   slo[4][ROWCAP];
    __shared__ float swt[4][ROWCAP];
    __shared__ u32   scnt[4];
    const int b = blockIdx.x, tid = threadIdx.x;
    const int wid = tid >> 6, lane = tid & 63;
    const int slane = lane & 15, f4 = lane >> 4;
    const int wave = b * 4 + wid;                  // 4096 waves
    #pragma unroll
    for (int rr = 0; rr < 2; ++rr) {
        int row = wave * 2 + rr;
        u32 len = min(cursor[row], (u32)ROWCAP);
        size_t base = (size_t)row * ROWCAP;
        if (lane == 0) scnt[wid] = 0;
        for (u32 i = lane; i < len; i += 64) {
            u64 v = rowdat[base + i];
            slo[wid][i] = (u32)v;                          // (c<<18)|eid
            swt[wid][i] = __uint_as_float((u32)(v >> 32));
        }
        // wave-private LDS slice: same-wave LDS ops are in-order, no syncthreads
        for (u32 i = lane; i < len; i += 64) {
            u32 lo = slo[wid][i];
            bool dead = false;
            for (u32 q = 0; q < len; ++q) {
                u32 o = slo[wid][q];
                dead |= ((o >> 18) == (lo >> 18)) && (o > lo);
            }
            if (dead) {
                swt[wid][i] = 0.f;
            } else {
                u32 pos = atomicAdd(&scnt[wid], 1u);       // LDS atomic
                rowdat2[(size_t)row * ROWCAP + pos] =
                    ((u64)(u32)__float_as_uint(swt[wid][i]) << 32) |
                    (u64)(lo >> 18);                       // {w:32 | c:13}
            }
        }
        if (lane == 0) cursor2[row] = scnt[wid];
        // spmm0: LDS weights (dups zeroed) x x0 gather, 16 slots x 4 f-groups
        f32x4 acc = {0.f, 0.f, 0.f, 0.f};
        for (u32 i = slane; i < len; i += 16) {
            float w = swt[wid][i];
            u32 c = slo[wid][i] >> 18;
            f32x4 h = *(const f32x4*)&x0[c * NIN + f4 * 4];
            acc += w * h;
        }
        #pragma unroll
        for (int d = 1; d < 16; d <<= 1) {
            acc.x += __shfl_xor(acc.x, d);
            acc.y += __shfl_xor(acc.y, d);
            acc.z += __shfl_xor(acc.z, d);
            acc.w += __shfl_xor(acc.w, d);
        }
        if (slane == 0) *(f32x4*)&out[row * NIN + f4 * 4] = acc;
    }
}

// D4-D6: spmm step k from compacted rows. 2 rows/wave, 16 slots x 4 f-groups.
__global__ void spmm_kernel(const u32* __restrict__ cursor2,
                            const u64* __restrict__ rowdat2,
                            const float* __restrict__ hin,
                            float* __restrict__ hout) {
    const int b = blockIdx.x, tid = threadIdx.x;
    const int wid = tid >> 6, lane = tid & 63;
    const int slane = lane & 15, f4 = lane >> 4;
    const int wave = b * 4 + wid;
    #pragma unroll
    for (int rr = 0; rr < 2; ++rr) {
        int row = wave * 2 + rr;
        u32 len = cursor2[row];
        const u64* rp = rowdat2 + (size_t)row * ROWCAP;
        f32x4 acc = {0.f, 0.f, 0.f, 0.f};
        for (u32 i = slane; i < len; i += 16) {
            u64 v = rp[i];
            float w = __uint_as_float((u32)(v >> 32));
            u32 c = (u32)v & 0x1FFFu;
            f32x4 h = *(const f32x4*)&hin[c * NIN + f4 * 4];
            acc += w * h;
        }
        #pragma unroll
        for (int d = 1; d < 16; d <<= 1) {
            acc.x += __shfl_xor(acc.x, d);
            acc.y += __shfl_xor(acc.y, d);
            acc.z += __shfl_xor(acc.z, d);
            acc.w += __shfl_xor(acc.w, d);
        }
        if (slane == 0) *(f32x4*)&hout[row * NIN + f4 * 4] = acc;
    }
}

extern "C" void kernel_launch(void* const* d_in, const int* in_sizes, int n_in,
                              void* d_out, int out_size, void* d_ws, size_t ws_size,
                              hipStream_t stream) {
    (void)in_sizes; (void)n_in; (void)out_size; (void)ws_size;
    const float* nf  = (const float*)d_in[0];
    const int*   ei  = (const int*)d_in[1];
    const float* ew  = (const float*)d_in[2];
    const float* emb = (const float*)d_in[3];
    float* out = (float*)d_out;

    char* ws = (char*)d_ws;
    size_t off = 0;
    auto alloc = [&](size_t bytes) {
        void* p = ws + off;
        off += (bytes + 255) & ~(size_t)255;
        return p;
    };
    u64*   rowdat  = (u64*)alloc((size_t)N_NODES * ROWCAP * 8);   // 6.3 MB
    u64*   rowdat2 = (u64*)alloc((size_t)N_NODES * ROWCAP * 8);   // 6.3 MB
    float* x0      = (float*)alloc((size_t)N_NODES * NIN * 4);    // 512 KB
    u32*   cursor  = (u32*)alloc((size_t)N_NODES * 4);            // 32 KB
    u32*   cursor2 = (u32*)alloc((size_t)N_NODES * 4);            // 32 KB

    init_kernel<<<4, NTHR, 0, stream>>>(cursor);
    embed_scatter_kernel<<<1024, NTHR, 0, stream>>>(nf, emb, ei, ew, x0, cursor, rowdat);
    dedup_spmm0_kernel<<<1024, NTHR, 0, stream>>>(cursor, rowdat, x0, rowdat2, cursor2, out);
    const float* hin = out;
    for (int k = 1; k < K_STEPS; ++k) {
        float* hout = out + (size_t)k * N_NODES * NIN;
        spmm_kernel<<<1024, NTHR, 0, stream>>>(cursor2, rowdat2, hin, hout);
        hin = hout;
    }
}